// Round 1
// baseline (167.748 us; speedup 1.0000x reference)
//
#include <hip/hip_runtime.h>
#include <hip/hip_bf16.h>

typedef unsigned int u32;
typedef unsigned short u16;
typedef float f32x4 __attribute__((ext_vector_type(4)));
typedef float f32x2 __attribute__((ext_vector_type(2)));
typedef short s16x8 __attribute__((ext_vector_type(8)));

#define B_   2
#define S_   2048
#define HID_ 512
#define H_   8
#define HKV_ 2
#define QB_  8
#define VB_  16
#define NQ_  64
#define NKC_ 16
#define NC_  112
#define HVB_ 128

__device__ __forceinline__ u16 f2bf(float f) {
    u32 b = __builtin_bit_cast(u32, f);
    b += 0x7FFFu + ((b >> 16) & 1u);
    return (u16)(b >> 16);
}
__device__ __forceinline__ float bf2f(u16 h) {
    u32 b = ((u32)h) << 16;
    return __builtin_bit_cast(float, b);
}
__device__ __forceinline__ f32x4 mfma16(s16x8 a, s16x8 b, f32x4 c) {
    return __builtin_amdgcn_mfma_f32_16x16x32_bf16(a, b, c, 0, 0, 0);
}

// ---------------------------------------------------------------- K0: weights -> bf16 hi/lo planes
__global__ void k0_convert(const float* __restrict__ Wq, const float* __restrict__ Wk,
                           const float* __restrict__ Wv, const float* __restrict__ Wo,
                           u16* __restrict__ Wc_hi, u16* __restrict__ Wc_lo,
                           u16* __restrict__ Wo_hi, u16* __restrict__ Wo_lo) {
    int idx = blockIdx.x * 256 + threadIdx.x;
    if (idx < NC_ * HID_) {
        int n = idx >> 9, c = idx & 511;
        float v = (n < NQ_) ? Wq[n * HID_ + c]
                : (n < NQ_ + NKC_) ? Wk[(n - NQ_) * HID_ + c]
                : Wv[(n - NQ_ - NKC_) * HID_ + c];
        u16 hi = f2bf(v);
        Wc_hi[idx] = hi;
        Wc_lo[idx] = f2bf(v - bf2f(hi));
    }
    if (idx < HID_ * HVB_) {
        float v = Wo[idx];
        u16 hi = f2bf(v);
        Wo_hi[idx] = hi;
        Wo_lo[idx] = f2bf(v - bf2f(hi));
    }
}

// ---------------------------------------------------------------- K1: projections (bf16x3 MFMA)
// grid 256 (16 rows each), block 64 (1 wave). out cols: 0..63 q(tanh), 64..79 k(tanh), 80..111 v(sigmoid,shifted)
__global__ __launch_bounds__(64) void k1_proj(
    const float* __restrict__ hidden,
    const u16* __restrict__ Wc_hi, const u16* __restrict__ Wc_lo,
    float* __restrict__ qg, float* __restrict__ kg, float* __restrict__ vsg)
{
    __shared__ __align__(16) u32 Ahi[16 * 256];
    __shared__ __align__(16) u32 Alo[16 * 256];
    const int tid = threadIdx.x;
    const int r0 = blockIdx.x * 16;

    for (int it = 0; it < 64; ++it) {
        int e2 = tid + 64 * it;            // 4096 float2 = 16x512
        int m = e2 >> 8, c2 = e2 & 255;
        f32x2 v = *(const f32x2*)&hidden[(r0 + m) * HID_ + 2 * c2];
        u16 h0 = f2bf(v[0]), h1 = f2bf(v[1]);
        Ahi[m * 256 + c2] = (u32)h0 | ((u32)h1 << 16);
        u16 l0 = f2bf(v[0] - bf2f(h0)), l1 = f2bf(v[1] - bf2f(h1));
        Alo[m * 256 + c2] = (u32)l0 | ((u32)l1 << 16);
    }
    __syncthreads();

    const int li = tid & 15, lo4 = tid >> 4;
    const u16* Ah16 = (const u16*)Ahi;
    const u16* Al16 = (const u16*)Alo;
    f32x4 acc[7];
    #pragma unroll
    for (int nf = 0; nf < 7; ++nf) acc[nf] = (f32x4){0.f, 0.f, 0.f, 0.f};

    for (int kc = 0; kc < 16; ++kc) {
        int k0 = kc * 32;
        s16x8 ah = *(const s16x8*)&Ah16[li * 512 + k0 + 8 * lo4];
        s16x8 al = *(const s16x8*)&Al16[li * 512 + k0 + 8 * lo4];
        #pragma unroll
        for (int nf = 0; nf < 7; ++nf) {
            int n = nf * 16 + li;
            s16x8 bh = *(const s16x8*)&Wc_hi[n * HID_ + k0 + 8 * lo4];
            s16x8 bl = *(const s16x8*)&Wc_lo[n * HID_ + k0 + 8 * lo4];
            acc[nf] = mfma16(ah, bh, acc[nf]);
            acc[nf] = mfma16(ah, bl, acc[nf]);
            acc[nf] = mfma16(al, bh, acc[nf]);
        }
    }

    #pragma unroll
    for (int nf = 0; nf < 7; ++nf) {
        int n = nf * 16 + li;
        #pragma unroll
        for (int reg = 0; reg < 4; ++reg) {
            int gs = r0 + 4 * lo4 + reg;
            int b = gs >> 11, s = gs & 2047;
            float pre = acc[nf][reg];
            if (n < NQ_) {
                float val = tanhf(pre);
                int h = n >> 3, bit = n & 7;
                qg[(((b * H_ + h) * S_) + s) * QB_ + bit] = val;
            } else if (n < NQ_ + NKC_) {
                float val = tanhf(pre);
                int nk = n - NQ_;
                kg[(((b * HKV_ + (nk >> 3)) * S_) + s) * QB_ + (nk & 7)] = val;
            } else {
                float val = 1.f / (1.f + expf(-pre));
                int nv = n - NQ_ - NKC_;
                int hv = nv >> 4, vb = nv & 15;
                if (s > 0)
                    vsg[(((b * HKV_ + hv) * S_) + (s - 1)) * VB_ + vb] = val;
                if (s == S_ - 1)
                    vsg[(((b * HKV_ + hv) * S_) + (S_ - 1)) * VB_ + vb] = 0.f;
            }
        }
    }
}

// ---------------------------------------------------------------- K2: fused windowed attention
// grid 512 = 32 row-blocks (heavy-first) x 16 (b,h); block 256 (4 waves, 16 rows each)
__global__ __launch_bounds__(256) void k2_attn(
    const float* __restrict__ qg, const float* __restrict__ kg,
    const float* __restrict__ vsg,
    const float* __restrict__ vemb0, const float* __restrict__ vemb1,
    float* __restrict__ AO)
{
    __shared__ __align__(16) u16 qs[96 * 8];
    __shared__ __align__(16) u16 ks[96 * 8];
    __shared__ __align__(16) u16 vts[16 * 72];
    __shared__ __align__(16) u16 ps[4 * 16 * 72];

    const int tid = threadIdx.x;
    const int bid = blockIdx.x;
    const int I0 = (31 - (bid >> 4)) * 64;
    const int bh = bid & 15;
    const int b = bh >> 3, h = bh & 7, hkv = h >> 2;

    const int qhb = ((b * H_ + h) * S_) * QB_;
    const int khb = ((b * HKV_ + hkv) * S_) * QB_;
    const int vhb = ((b * HKV_ + hkv) * S_) * VB_;

    {   // q rows [I0-31, I0+63] -> bf16 LDS (rows < 0 zeroed)
        int g0 = (I0 - 31) * 8;
        for (int e = tid; e < 760; e += 256) {
            float v = (g0 + e >= 0) ? qg[qhb + g0 + e] : 0.f;
            qs[e] = f2bf(v);
        }
    }
    __syncthreads();

    const int w = tid >> 6, lane = tid & 63;
    const int li = lane & 15, lo4 = lane >> 4;
    u16* psw = ps + w * (16 * 72);

    // q fragments are J-invariant: hoist
    s16x8 af[8];
    #pragma unroll
    for (int kk = 0; kk < 8; ++kk)
        af[kk] = *(const s16x8*)&qs[(16 * w + li + 4 * kk + lo4) * 8];

    float binv[4];
    #pragma unroll
    for (int reg = 0; reg < 4; ++reg)
        binv[reg] = 1.f / (float)(I0 + 16 * w + 4 * lo4 + reg + 1);

    f32x4 O = (f32x4){0.f, 0.f, 0.f, 0.f};
    float m_run[4] = {-1e30f, -1e30f, -1e30f, -1e30f};
    float l_run[4] = {0.f, 0.f, 0.f, 0.f};

    const int nJ = I0 / 64 + 1;
    for (int jt = 0; jt < nJ; ++jt) {
        const int J0 = jt * 64;
        __syncthreads();   // protect ks/vts from previous iteration's readers
        {
            int g0 = (J0 - 31) * 8;
            for (int e = tid; e < 760; e += 256) {
                float v = (g0 + e >= 0) ? kg[khb + g0 + e] : 0.f;
                ks[e] = f2bf(v);
            }
            int vb0 = J0 * VB_;
            for (int e = tid; e < 1024; e += 256) {
                int j = e >> 4, vb = e & 15;
                vts[vb * 72 + j] = f2bf(vsg[vhb + vb0 + e]);
            }
        }
        __syncthreads();

        // QK^T with implicit window-unfold (K=256)
        f32x4 sacc[4];
        #pragma unroll
        for (int ns = 0; ns < 4; ++ns) {
            sacc[ns] = (f32x4){0.f, 0.f, 0.f, 0.f};
            #pragma unroll
            for (int kk = 0; kk < 8; ++kk) {
                s16x8 bf = *(const s16x8*)&ks[(16 * ns + li + 4 * kk + lo4) * 8];
                sacc[ns] = mfma16(af[kk], bf, sacc[ns]);
            }
        }

        // bias + strict causal mask + online softmax; P -> LDS (bf16)
        #pragma unroll
        for (int reg = 0; reg < 4; ++reg) {
            const int i = I0 + 16 * w + 4 * lo4 + reg;
            float sv[4];
            float mrow = -1e30f;
            #pragma unroll
            for (int ns = 0; ns < 4; ++ns) {
                int j = J0 + 16 * ns + li;
                float s = (j < i) ? fmaf(sacc[ns][reg], 0.0625f, (float)j * binv[reg])
                                  : -1e30f;
                sv[ns] = s;
                mrow = fmaxf(mrow, s);
            }
            mrow = fmaxf(mrow, __shfl_xor(mrow, 1));
            mrow = fmaxf(mrow, __shfl_xor(mrow, 2));
            mrow = fmaxf(mrow, __shfl_xor(mrow, 4));
            mrow = fmaxf(mrow, __shfl_xor(mrow, 8));
            float mnew = fmaxf(m_run[reg], mrow);
            float alpha = __expf(m_run[reg] - mnew);
            m_run[reg] = mnew;
            float rs = 0.f;
            #pragma unroll
            for (int ns = 0; ns < 4; ++ns) {
                int j = J0 + 16 * ns + li;
                float p = (j < i) ? __expf(sv[ns] - mnew) : 0.f;
                rs += p;
                psw[(4 * lo4 + reg) * 72 + 16 * ns + li] = f2bf(p);
            }
            rs += __shfl_xor(rs, 1);
            rs += __shfl_xor(rs, 2);
            rs += __shfl_xor(rs, 4);
            rs += __shfl_xor(rs, 8);
            l_run[reg] = l_run[reg] * alpha + rs;
            O[reg] *= alpha;
        }

        // PV (K=64 over this J tile)
        #pragma unroll
        for (int kk2 = 0; kk2 < 2; ++kk2) {
            s16x8 pa = *(const s16x8*)&psw[li * 72 + 32 * kk2 + 8 * lo4];
            s16x8 pb = *(const s16x8*)&vts[li * 72 + 32 * kk2 + 8 * lo4];
            O = mfma16(pa, pb, O);
        }
    }

    // epilogue: normalize + v_emb interpolation -> AO [B*S, 128]
    #pragma unroll
    for (int reg = 0; reg < 4; ++reg) {
        int s = I0 + 16 * w + 4 * lo4 + reg;
        int hc = h * VB_ + li;
        float denom = fmaxf(l_run[reg], 1e-30f);
        float o = O[reg] / denom;
        float e0 = vemb0[hc], e1 = vemb1[hc];
        AO[(b * S_ + s) * HVB_ + hc] = o * e1 + (1.f - o) * e0;
    }
}

// ---------------------------------------------------------------- K3: AO @ Wo^T (bf16x3 MFMA)
// grid 512 = 256 row-tiles x 2 col-halves; block 64 (1 wave)
__global__ __launch_bounds__(64) void k3_out(
    const float* __restrict__ AO,
    const u16* __restrict__ Wo_hi, const u16* __restrict__ Wo_lo,
    float* __restrict__ out)
{
    __shared__ __align__(16) u32 Ahi[16 * 64];
    __shared__ __align__(16) u32 Alo[16 * 64];
    const int tid = threadIdx.x;
    const int mb = blockIdx.x >> 1, nb = blockIdx.x & 1;
    const int r0 = mb * 16;

    for (int it = 0; it < 16; ++it) {
        int e2 = tid + 64 * it;            // 1024 float2 = 16x128
        int m = e2 >> 6, c2 = e2 & 63;
        f32x2 v = *(const f32x2*)&AO[(r0 + m) * HVB_ + 2 * c2];
        u16 h0 = f2bf(v[0]), h1 = f2bf(v[1]);
        Ahi[m * 64 + c2] = (u32)h0 | ((u32)h1 << 16);
        u16 l0 = f2bf(v[0] - bf2f(h0)), l1 = f2bf(v[1] - bf2f(h1));
        Alo[m * 64 + c2] = (u32)l0 | ((u32)l1 << 16);
    }
    __syncthreads();

    const int li = tid & 15, lo4 = tid >> 4;
    const u16* Ah16 = (const u16*)Ahi;
    const u16* Al16 = (const u16*)Alo;
    f32x4 acc[16];
    #pragma unroll
    for (int nf = 0; nf < 16; ++nf) acc[nf] = (f32x4){0.f, 0.f, 0.f, 0.f};

    #pragma unroll
    for (int kc = 0; kc < 4; ++kc) {
        int k0 = kc * 32;
        s16x8 ah = *(const s16x8*)&Ah16[li * 128 + k0 + 8 * lo4];
        s16x8 al = *(const s16x8*)&Al16[li * 128 + k0 + 8 * lo4];
        #pragma unroll
        for (int nf = 0; nf < 16; ++nf) {
            int o = nb * 256 + nf * 16 + li;
            s16x8 bh = *(const s16x8*)&Wo_hi[o * HVB_ + k0 + 8 * lo4];
            s16x8 bl = *(const s16x8*)&Wo_lo[o * HVB_ + k0 + 8 * lo4];
            acc[nf] = mfma16(ah, bh, acc[nf]);
            acc[nf] = mfma16(ah, bl, acc[nf]);
            acc[nf] = mfma16(al, bh, acc[nf]);
        }
    }

    #pragma unroll
    for (int nf = 0; nf < 16; ++nf) {
        int o = nb * 256 + nf * 16 + li;
        #pragma unroll
        for (int reg = 0; reg < 4; ++reg) {
            out[(r0 + 4 * lo4 + reg) * HID_ + o] = acc[nf][reg];
        }
    }
}

// ---------------------------------------------------------------- launch
extern "C" void kernel_launch(void* const* d_in, const int* in_sizes, int n_in,
                              void* d_out, int out_size, void* d_ws, size_t ws_size,
                              hipStream_t stream)
{
    const float* hidden = (const float*)d_in[0];
    const float* Wq = (const float*)d_in[1];
    const float* Wk = (const float*)d_in[2];
    const float* Wv = (const float*)d_in[3];
    const float* Wo = (const float*)d_in[4];
    const float* ve0 = (const float*)d_in[5];
    const float* ve1 = (const float*)d_in[6];
    float* out = (float*)d_out;

    float* qg  = (float*)d_ws;                 // [B,H,S,QB]   262144 f
    float* kg  = qg + 262144;                  // [B,HKV,S,QB]  65536 f
    float* vsg = kg + 65536;                   // [B,HKV,S,VB] 131072 f (shifted v)
    float* AO  = vsg + 131072;                 // [B*S,128]    524288 f
    u16* Wc_hi = (u16*)(AO + 524288);          // [112,512]
    u16* Wc_lo = Wc_hi + 57344;
    u16* Wo_hi = Wc_lo + 57344;                // [512,128]
    u16* Wo_lo = Wo_hi + 65536;
    if (ws_size < 4423680) return;

    hipLaunchKernelGGL(k0_convert, dim3(256), dim3(256), 0, stream,
                       Wq, Wk, Wv, Wo, Wc_hi, Wc_lo, Wo_hi, Wo_lo);
    hipLaunchKernelGGL(k1_proj, dim3(256), dim3(64), 0, stream,
                       hidden, Wc_hi, Wc_lo, qg, kg, vsg);
    hipLaunchKernelGGL(k2_attn, dim3(512), dim3(256), 0, stream,
                       qg, kg, vsg, ve0, ve1, AO);
    hipLaunchKernelGGL(k3_out, dim3(512), dim3(64), 0, stream,
                       AO, Wo_hi, Wo_lo, out);
}

// Round 2
// 64.250 us; speedup vs baseline: 2.6108x; 2.6108x over previous
//
#include <hip/hip_runtime.h>
#include <hip/hip_bf16.h>

typedef unsigned int u32;
typedef unsigned short u16;
typedef float f32x4 __attribute__((ext_vector_type(4)));
typedef short s16x8 __attribute__((ext_vector_type(8)));
typedef u32 u32x2 __attribute__((ext_vector_type(2)));

#define B_   2
#define S_   2048
#define HID_ 512
#define H_   8
#define HKV_ 2
#define QB_  8
#define VB_  16
#define NQ_  64
#define NC_  112
#define HVB_ 128
#define SCALE_ 0.0625f
#define MFIX_  17.0f

__device__ __forceinline__ u16 f2bf(float f) {
    u32 b = __builtin_bit_cast(u32, f);
    b += 0x7FFFu + ((b >> 16) & 1u);
    return (u16)(b >> 16);
}
__device__ __forceinline__ float bf2f(u16 h) {
    u32 b = ((u32)h) << 16;
    return __builtin_bit_cast(float, b);
}
__device__ __forceinline__ f32x4 mfma16(s16x8 a, s16x8 b, f32x4 c) {
    return __builtin_amdgcn_mfma_f32_16x16x32_bf16(a, b, c, 0, 0, 0);
}

// ------------------------------------------------- K0: weights -> bf16 hi/lo, frag-swizzled
// W2c layout: ((k>>5)*112 + n)*32 + (k&31)   (k-chunk-major, frag-load contiguous)
// W2o layout: ((k>>5)*512 + o)*32 + (k&31)
__global__ void k0_convert(const float* __restrict__ Wq, const float* __restrict__ Wk,
                           const float* __restrict__ Wv, const float* __restrict__ Wo,
                           u16* __restrict__ W2c_hi, u16* __restrict__ W2c_lo,
                           u16* __restrict__ W2o_hi, u16* __restrict__ W2o_lo) {
    int idx = blockIdx.x * 256 + threadIdx.x;
    if (idx < NC_ * HID_) {
        int n = idx >> 9, k = idx & 511;
        float v = (n < NQ_) ? Wq[n * HID_ + k]
                : (n < NQ_ + 16) ? Wk[(n - NQ_) * HID_ + k]
                : Wv[(n - NQ_ - 16) * HID_ + k];
        int dst = ((k >> 5) * NC_ + n) * 32 + (k & 31);
        u16 hi = f2bf(v);
        W2c_hi[dst] = hi;
        W2c_lo[dst] = f2bf(v - bf2f(hi));
    }
    if (idx < HID_ * HVB_) {
        int o = idx >> 7, k = idx & 127;
        float v = Wo[idx];
        int dst = ((k >> 5) * HID_ + o) * 32 + (k & 31);
        u16 hi = f2bf(v);
        W2o_hi[dst] = hi;
        W2o_lo[dst] = f2bf(v - bf2f(hi));
    }
}

// ------------------------------------------------- K1: projections -> bf16 qb/kb/vt
// block 256 (4 waves), 16 rows; wave wv owns frags {wv, wv+4}
__global__ __launch_bounds__(256) void k1_proj(
    const float* __restrict__ hidden,
    const u16* __restrict__ W2c_hi, const u16* __restrict__ W2c_lo,
    u16* __restrict__ qb, u16* __restrict__ kb, u16* __restrict__ vt)
{
    __shared__ __align__(16) u32 Ahi[16 * 256];
    __shared__ __align__(16) u32 Alo[16 * 256];
    char* AhiB = (char*)Ahi;
    char* AloB = (char*)Alo;
    const int tid = threadIdx.x;
    const int r0 = blockIdx.x * 16;

    #pragma unroll
    for (int it = 0; it < 8; ++it) {
        int v4 = it * 256 + tid;            // 2048 f32x4 = 16 x 512
        int m = v4 >> 7, c4 = v4 & 127;
        f32x4 x = *(const f32x4*)&hidden[(r0 + m) * HID_ + 4 * c4];
        u16 h0 = f2bf(x[0]), h1 = f2bf(x[1]), h2 = f2bf(x[2]), h3 = f2bf(x[3]);
        u16 l0 = f2bf(x[0] - bf2f(h0)), l1 = f2bf(x[1] - bf2f(h1));
        u16 l2 = f2bf(x[2] - bf2f(h2)), l3 = f2bf(x[3] - bf2f(h3));
        int byt = (c4 * 8) ^ ((m & 7) << 4);   // XOR swizzle: row-stride 1KB is 16-way conflict otherwise
        *(u32x2*)(AhiB + m * 1024 + byt) = (u32x2){(u32)h0 | ((u32)h1 << 16), (u32)h2 | ((u32)h3 << 16)};
        *(u32x2*)(AloB + m * 1024 + byt) = (u32x2){(u32)l0 | ((u32)l1 << 16), (u32)l2 | ((u32)l3 << 16)};
    }
    __syncthreads();

    const int wv = tid >> 6, lane = tid & 63;
    const int li = lane & 15, lo4 = lane >> 4;
    const int nf = (wv == 3) ? 1 : 2;
    const int fl[2] = {wv, wv + 4};

    f32x4 acc[2];
    acc[0] = (f32x4){0.f, 0.f, 0.f, 0.f};
    acc[1] = (f32x4){0.f, 0.f, 0.f, 0.f};

    for (int kc = 0; kc < 16; ++kc) {
        int off = (64 * kc + 16 * lo4) ^ ((li & 7) << 4);
        s16x8 ah = *(const s16x8*)(AhiB + li * 1024 + off);
        s16x8 al = *(const s16x8*)(AloB + li * 1024 + off);
        #pragma unroll
        for (int u = 0; u < 2; ++u) {
            if (u < nf) {
                int n = fl[u] * 16 + li;
                int bidx = (kc * NC_ + n) * 32 + 8 * lo4;
                s16x8 bh = *(const s16x8*)&W2c_hi[bidx];
                s16x8 bl = *(const s16x8*)&W2c_lo[bidx];
                acc[u] = mfma16(ah, bh, acc[u]);
                acc[u] = mfma16(ah, bl, acc[u]);
                acc[u] = mfma16(al, bh, acc[u]);
            }
        }
    }

    #pragma unroll
    for (int u = 0; u < 2; ++u) {
        if (u < nf) {
            int n = fl[u] * 16 + li;
            #pragma unroll
            for (int reg = 0; reg < 4; ++reg) {
                int gs = r0 + 4 * lo4 + reg;
                int b = gs >> 11, s = gs & 2047;
                float pre = acc[u][reg];
                if (n < NQ_) {
                    int h = n >> 3, bit = n & 7;
                    qb[(((b * H_ + h) * S_) + s) * QB_ + bit] = f2bf(tanhf(pre));
                } else if (n < NQ_ + 16) {
                    int nk = n - NQ_;
                    kb[(((b * HKV_ + (nk >> 3)) * S_) + s) * QB_ + (nk & 7)] = f2bf(tanhf(pre));
                } else {
                    int nv = n - NQ_ - 16;
                    int hv = nv >> 4, vb = nv & 15;
                    u16 sig = f2bf(1.f / (1.f + __expf(-pre)));
                    if (s > 0)
                        vt[((b * HKV_ + hv) * VB_ + vb) * S_ + (s - 1)] = sig;   // suffix shift
                    if (s == S_ - 1)
                        vt[((b * HKV_ + hv) * VB_ + vb) * S_ + (S_ - 1)] = 0;
                }
            }
        }
    }
}

// ------------------------------------------------- K2: fused windowed attention
// grid 512 = 32 row-blocks x 16 bh; block 512 (8 waves = 2 J-groups x 4 row-waves)
// fixed-max softmax (scores provably in (-16,17) -> M=17), J-partials merge by plain sum
__global__ __launch_bounds__(512, 4) void k2_attn(
    const u16* __restrict__ qb, const u16* __restrict__ kb, const u16* __restrict__ vt,
    const float* __restrict__ vemb0, const float* __restrict__ vemb1,
    float* __restrict__ AO)
{
    __shared__ __align__(16) u16 ks[2][2][96 * 8];     // [group][dbuf][rows 0..95]
    __shared__ __align__(16) u16 psa[8][16 * 72];
    __shared__ __align__(16) float Om[8][16][17];
    __shared__ float lv[8][16];

    const int tid = threadIdx.x;
    const int bid = blockIdx.x;
    const int rb = bid >> 4;
    const int r  = (rb < 16) ? (31 - rb) : (rb - 16);  // complementary pairing: work(bid)+work(bid+256) const
    const int I0 = r * 64;
    const int nJ = r + 1;
    const int bh = bid & 15;
    const int b = bh >> 3, h = bh & 7, hkv = h >> 2;

    const int qhb = ((b * H_ + h) * S_) * QB_;
    const int khb = ((b * HKV_ + hkv) * S_) * QB_;
    const int vhb = ((b * HKV_ + hkv) * VB_) * S_;

    const int w = tid >> 6, lane = tid & 63;
    const int g = w >> 2, wr = w & 3;
    const int li = lane & 15, lo4 = lane >> 4;
    const int tloc = tid & 255;

    u16* psw = psa[w];

    // hoist Q fragments (direct from global; zero-pad rows < 0)
    s16x8 af[8];
    {
        const int gr0 = I0 - 31 + 16 * wr + li + lo4;
        const u16* qp = qb + qhb + gr0 * QB_;
        #pragma unroll
        for (int kk = 0; kk < 8; ++kk) {
            s16x8 v = {0, 0, 0, 0, 0, 0, 0, 0};
            if (gr0 + 4 * kk >= 0) v = *(const s16x8*)(qp + kk * 32);
            af[kk] = v;
        }
    }

    int iv[4];
    float binv[4];
    #pragma unroll
    for (int reg = 0; reg < 4; ++reg) {
        iv[reg] = I0 + 16 * wr + 4 * lo4 + reg;
        binv[reg] = 1.0f / (float)(iv[reg] + 1);
    }

    f32x4 O = (f32x4){0.f, 0.f, 0.f, 0.f};
    float lsum[4] = {0.f, 0.f, 0.f, 0.f};

    const u16* vtp = vt + vhb + li * S_ + 8 * lo4;

    // prologue: stage tile jt = g into buf 0
    if (g < nJ && tloc < 96) {
        int gr = 64 * g - 31 + tloc;
        s16x8 v = {0, 0, 0, 0, 0, 0, 0, 0};
        if (gr >= 0) v = *(const s16x8*)(kb + khb + gr * QB_);
        *(s16x8*)&ks[g][0][tloc * 8] = v;
    }
    __syncthreads();

    const int nT = (nJ + 1) >> 1;
    for (int t = 0; t < nT; ++t) {
        const int cb = t & 1;
        const int jt = 2 * t + g;

        // T14 split: issue next-tile global load EARLY (reg), ds_write LATE (after compute)
        const bool do_stage = ((jt + 2) < nJ) && (tloc < 96);
        s16x8 stg;
        if (do_stage)
            stg = *(const s16x8*)(kb + khb + (64 * (jt + 2) - 31 + tloc) * QB_);

        if (jt < nJ) {
            // QK^T, implicit window-unfold, K=256
            const u16* kbuf = &ks[g][cb][(li + lo4) * 8];
            f32x4 sacc[4];
            #pragma unroll
            for (int ns = 0; ns < 4; ++ns) {
                sacc[ns] = (f32x4){0.f, 0.f, 0.f, 0.f};
                #pragma unroll
                for (int kk = 0; kk < 8; ++kk) {
                    s16x8 bf = *(const s16x8*)(kbuf + (16 * ns + 4 * kk) * 8);
                    sacc[ns] = mfma16(af[kk], bf, sacc[ns]);
                }
            }
            // bias + strict mask + fixed-max exp; P -> per-wave LDS
            const int J0 = jt * 64;
            int jv[4];
            #pragma unroll
            for (int ns = 0; ns < 4; ++ns) jv[ns] = J0 + 16 * ns + li;
            #pragma unroll
            for (int reg = 0; reg < 4; ++reg) {
                #pragma unroll
                for (int ns = 0; ns < 4; ++ns) {
                    float s = fmaf(sacc[ns][reg], SCALE_, (float)jv[ns] * binv[reg]);
                    float p = (jv[ns] < iv[reg]) ? __expf(s - MFIX_) : 0.0f;
                    lsum[reg] += p;
                    psw[(4 * lo4 + reg) * 72 + 16 * ns + li] = f2bf(p);
                }
            }
            // PV: P from LDS, V^T direct from global (L2-resident)
            #pragma unroll
            for (int kk2 = 0; kk2 < 2; ++kk2) {
                s16x8 pa = *(const s16x8*)&psw[li * 72 + 32 * kk2 + 8 * lo4];
                s16x8 pb = *(const s16x8*)(vtp + J0 + 32 * kk2);
                O = mfma16(pa, pb, O);
            }
        }

        if (do_stage)
            *(s16x8*)&ks[g][cb ^ 1][tloc * 8] = stg;

        __syncthreads();
    }

    // publish partials (plain-sum merge: fixed max => no exp rescale)
    #pragma unroll
    for (int reg = 0; reg < 4; ++reg) {
        float l = lsum[reg];
        l += __shfl_xor(l, 1);
        l += __shfl_xor(l, 2);
        l += __shfl_xor(l, 4);
        l += __shfl_xor(l, 8);
        Om[w][4 * lo4 + reg][li] = O[reg];
        if (li == 0) lv[w][4 * lo4 + reg] = l;
    }
    __syncthreads();

    if (g == 0) {
        const int hc = h * VB_ + li;
        const float e0 = vemb0[hc], e1 = vemb1[hc];
        #pragma unroll
        for (int reg = 0; reg < 4; ++reg) {
            const int row = 4 * lo4 + reg;
            float Oc = Om[w][row][li] + Om[w + 4][row][li];
            float lc = lv[w][row] + lv[w + 4][row];
            float o = Oc / fmaxf(lc, 1e-30f);
            const int s = I0 + 16 * wr + row;
            AO[(b * S_ + s) * HVB_ + hc] = e0 + o * (e1 - e0);
        }
    }
}

// ------------------------------------------------- K3: AO @ Wo^T (bf16x3)
// block 256 (4 waves), 16 rows x 512 cols; wave owns 8 frags
__global__ __launch_bounds__(256) void k3_out(
    const float* __restrict__ AO,
    const u16* __restrict__ W2o_hi, const u16* __restrict__ W2o_lo,
    float* __restrict__ out)
{
    __shared__ __align__(16) u32 Ahi[16 * 64];
    __shared__ __align__(16) u32 Alo[16 * 64];
    char* AhiB = (char*)Ahi;
    char* AloB = (char*)Alo;
    const int tid = threadIdx.x;
    const int r0 = blockIdx.x * 16;

    #pragma unroll
    for (int it = 0; it < 2; ++it) {
        int v4 = it * 256 + tid;            // 512 f32x4 = 16 x 128
        int m = v4 >> 5, c4 = v4 & 31;
        f32x4 x = *(const f32x4*)&AO[(r0 + m) * HVB_ + 4 * c4];
        u16 h0 = f2bf(x[0]), h1 = f2bf(x[1]), h2 = f2bf(x[2]), h3 = f2bf(x[3]);
        u16 l0 = f2bf(x[0] - bf2f(h0)), l1 = f2bf(x[1] - bf2f(h1));
        u16 l2 = f2bf(x[2] - bf2f(h2)), l3 = f2bf(x[3] - bf2f(h3));
        int byt = (c4 * 8) ^ ((m & 7) << 4);
        *(u32x2*)(AhiB + m * 256 + byt) = (u32x2){(u32)h0 | ((u32)h1 << 16), (u32)h2 | ((u32)h3 << 16)};
        *(u32x2*)(AloB + m * 256 + byt) = (u32x2){(u32)l0 | ((u32)l1 << 16), (u32)l2 | ((u32)l3 << 16)};
    }
    __syncthreads();

    const int wv = tid >> 6, lane = tid & 63;
    const int li = lane & 15, lo4 = lane >> 4;

    f32x4 acc[8];
    #pragma unroll
    for (int f = 0; f < 8; ++f) acc[f] = (f32x4){0.f, 0.f, 0.f, 0.f};

    #pragma unroll
    for (int kc = 0; kc < 4; ++kc) {
        int off = (64 * kc + 16 * lo4) ^ ((li & 7) << 4);
        s16x8 ah = *(const s16x8*)(AhiB + li * 256 + off);
        s16x8 al = *(const s16x8*)(AloB + li * 256 + off);
        #pragma unroll
        for (int f = 0; f < 8; ++f) {
            int o = wv * 128 + f * 16 + li;
            int bidx = (kc * HID_ + o) * 32 + 8 * lo4;
            s16x8 bh = *(const s16x8*)&W2o_hi[bidx];
            s16x8 bl = *(const s16x8*)&W2o_lo[bidx];
            acc[f] = mfma16(ah, bh, acc[f]);
            acc[f] = mfma16(ah, bl, acc[f]);
            acc[f] = mfma16(al, bh, acc[f]);
        }
    }

    #pragma unroll
    for (int f = 0; f < 8; ++f) {
        int o = wv * 128 + f * 16 + li;
        #pragma unroll
        for (int reg = 0; reg < 4; ++reg)
            out[(r0 + 4 * lo4 + reg) * HID_ + o] = acc[f][reg];
    }
}

// ------------------------------------------------- launch
extern "C" void kernel_launch(void* const* d_in, const int* in_sizes, int n_in,
                              void* d_out, int out_size, void* d_ws, size_t ws_size,
                              hipStream_t stream)
{
    (void)in_sizes; (void)n_in; (void)out_size;
    const float* hidden = (const float*)d_in[0];
    const float* Wq = (const float*)d_in[1];
    const float* Wk = (const float*)d_in[2];
    const float* Wv = (const float*)d_in[3];
    const float* Wo = (const float*)d_in[4];
    const float* ve0 = (const float*)d_in[5];
    const float* ve1 = (const float*)d_in[6];
    float* out = (float*)d_out;

    char* base = (char*)d_ws;
    u16* qb    = (u16*)(base);                      // [B,H,S,8]    524288 B
    u16* kb    = (u16*)(base + 524288);             // [B,HKV,S,8]  131072 B
    u16* vt    = (u16*)(base + 655360);             // [B,HKV,16,S] 262144 B (shifted, transposed)
    float* AO  = (float*)(base + 917504);           // [B*S,128]    2097152 B
    u16* W2c_hi = (u16*)(base + 3014656);           // 114688 B
    u16* W2c_lo = (u16*)(base + 3129344);           // 114688 B
    u16* W2o_hi = (u16*)(base + 3244032);           // 131072 B
    u16* W2o_lo = (u16*)(base + 3375104);           // 131072 B -> end 3506176
    if (ws_size < 3506176) return;

    hipLaunchKernelGGL(k0_convert, dim3(256), dim3(256), 0, stream,
                       Wq, Wk, Wv, Wo, W2c_hi, W2c_lo, W2o_hi, W2o_lo);
    hipLaunchKernelGGL(k1_proj, dim3(256), dim3(256), 0, stream,
                       hidden, W2c_hi, W2c_lo, qb, kb, vt);
    hipLaunchKernelGGL(k2_attn, dim3(512), dim3(512), 0, stream,
                       qb, kb, vt, ve0, ve1, AO);
    hipLaunchKernelGGL(k3_out, dim3(256), dim3(256), 0, stream,
                       AO, W2o_hi, W2o_lo, out);
}

// Round 6
// 63.658 us; speedup vs baseline: 2.6351x; 1.0093x over previous
//
#include <hip/hip_runtime.h>
#include <hip/hip_bf16.h>

typedef unsigned int u32;
typedef unsigned short u16;
typedef float f32x4 __attribute__((ext_vector_type(4)));
typedef short s16x8 __attribute__((ext_vector_type(8)));
typedef u32 u32x2 __attribute__((ext_vector_type(2)));

#define B_   2
#define S_   2048
#define HID_ 512
#define H_   8
#define HKV_ 2
#define QB_  8
#define VB_  16
#define NQ_  64
#define NC_  112
#define HVB_ 128
#define SCALE_ 0.0625f
#define MFIX_  17.0f

__device__ __forceinline__ u16 f2bf(float f) {
    u32 b = __builtin_bit_cast(u32, f);
    b += 0x7FFFu + ((b >> 16) & 1u);
    return (u16)(b >> 16);
}
__device__ __forceinline__ float bf2f(u16 h) {
    u32 b = ((u32)h) << 16;
    return __builtin_bit_cast(float, b);
}
__device__ __forceinline__ f32x4 mfma16(s16x8 a, s16x8 b, f32x4 c) {
    return __builtin_amdgcn_mfma_f32_16x16x32_bf16(a, b, c, 0, 0, 0);
}
// NaN-free by range analysis: e in [0,inf] -> rcp in [0,1] -> result in [-1,1].
__device__ __forceinline__ float fast_tanh(float x) {
    float e = __expf(2.f * x);
    return 1.f - 2.f * __builtin_amdgcn_rcpf(e + 1.f);
}
__device__ __forceinline__ float fast_sigmoid(float x) {
    return __builtin_amdgcn_rcpf(1.f + __expf(-x));
}

// ------------------------------------------------- K0: weights -> bf16 hi/lo, frag-swizzled
// W2c layout: ((k>>5)*112 + n)*32 + (k&31)   (k-chunk-major, frag-load contiguous)
// W2o layout: ((k>>5)*512 + o)*32 + (k&31)
__global__ void k0_convert(const float* __restrict__ Wq, const float* __restrict__ Wk,
                           const float* __restrict__ Wv, const float* __restrict__ Wo,
                           u16* __restrict__ W2c_hi, u16* __restrict__ W2c_lo,
                           u16* __restrict__ W2o_hi, u16* __restrict__ W2o_lo) {
    int idx = blockIdx.x * 256 + threadIdx.x;
    if (idx < NC_ * HID_) {
        int n = idx >> 9, k = idx & 511;
        float v = (n < NQ_) ? Wq[n * HID_ + k]
                : (n < NQ_ + 16) ? Wk[(n - NQ_) * HID_ + k]
                : Wv[(n - NQ_ - 16) * HID_ + k];
        int dst = ((k >> 5) * NC_ + n) * 32 + (k & 31);
        u16 hi = f2bf(v);
        W2c_hi[dst] = hi;
        W2c_lo[dst] = f2bf(v - bf2f(hi));
    }
    if (idx < HID_ * HVB_) {
        int o = idx >> 7, k = idx & 127;
        float v = Wo[idx];
        int dst = ((k >> 5) * HID_ + o) * 32 + (k & 31);
        u16 hi = f2bf(v);
        W2o_hi[dst] = hi;
        W2o_lo[dst] = f2bf(v - bf2f(hi));
    }
}

// ------------------------------------------------- K1: projections -> bf16 qb/kb/vt
// block 256 (4 waves), 16 rows; wave wv owns frags {wv, wv+4}
__global__ __launch_bounds__(256) void k1_proj(
    const float* __restrict__ hidden,
    const u16* __restrict__ W2c_hi, const u16* __restrict__ W2c_lo,
    u16* __restrict__ qb, u16* __restrict__ kb, u16* __restrict__ vt)
{
    __shared__ __align__(16) u32 Ahi[16 * 256];
    __shared__ __align__(16) u32 Alo[16 * 256];
    char* AhiB = (char*)Ahi;
    char* AloB = (char*)Alo;
    const int tid = threadIdx.x;
    const int r0 = blockIdx.x * 16;

    #pragma unroll
    for (int it = 0; it < 8; ++it) {
        int v4 = it * 256 + tid;            // 2048 f32x4 = 16 x 512
        int m = v4 >> 7, c4 = v4 & 127;
        f32x4 x = *(const f32x4*)&hidden[(r0 + m) * HID_ + 4 * c4];
        u16 h0 = f2bf(x[0]), h1 = f2bf(x[1]), h2 = f2bf(x[2]), h3 = f2bf(x[3]);
        u16 l0 = f2bf(x[0] - bf2f(h0)), l1 = f2bf(x[1] - bf2f(h1));
        u16 l2 = f2bf(x[2] - bf2f(h2)), l3 = f2bf(x[3] - bf2f(h3));
        int byt = (c4 * 8) ^ ((m & 7) << 4);   // XOR swizzle: row-stride 1KB is 16-way conflict otherwise
        *(u32x2*)(AhiB + m * 1024 + byt) = (u32x2){(u32)h0 | ((u32)h1 << 16), (u32)h2 | ((u32)h3 << 16)};
        *(u32x2*)(AloB + m * 1024 + byt) = (u32x2){(u32)l0 | ((u32)l1 << 16), (u32)l2 | ((u32)l3 << 16)};
    }
    __syncthreads();

    const int wv = tid >> 6, lane = tid & 63;
    const int li = lane & 15, lo4 = lane >> 4;
    const int nf = (wv == 3) ? 1 : 2;
    const int fl[2] = {wv, wv + 4};

    f32x4 acc[2];
    acc[0] = (f32x4){0.f, 0.f, 0.f, 0.f};
    acc[1] = (f32x4){0.f, 0.f, 0.f, 0.f};

    for (int kc = 0; kc < 16; ++kc) {
        int off = (64 * kc + 16 * lo4) ^ ((li & 7) << 4);
        s16x8 ah = *(const s16x8*)(AhiB + li * 1024 + off);
        s16x8 al = *(const s16x8*)(AloB + li * 1024 + off);
        #pragma unroll
        for (int u = 0; u < 2; ++u) {
            if (u < nf) {
                int n = fl[u] * 16 + li;
                int bidx = (kc * NC_ + n) * 32 + 8 * lo4;
                s16x8 bh = *(const s16x8*)&W2c_hi[bidx];
                s16x8 bl = *(const s16x8*)&W2c_lo[bidx];
                acc[u] = mfma16(ah, bh, acc[u]);
                acc[u] = mfma16(ah, bl, acc[u]);
                acc[u] = mfma16(al, bh, acc[u]);
            }
        }
    }

    #pragma unroll
    for (int u = 0; u < 2; ++u) {
        if (u < nf) {
            int n = fl[u] * 16 + li;
            #pragma unroll
            for (int reg = 0; reg < 4; ++reg) {
                int gs = r0 + 4 * lo4 + reg;
                int b = gs >> 11, s = gs & 2047;
                float pre = acc[u][reg];
                if (n < NQ_) {
                    int h = n >> 3, bit = n & 7;
                    qb[(((b * H_ + h) * S_) + s) * QB_ + bit] = f2bf(fast_tanh(pre));
                } else if (n < NQ_ + 16) {
                    int nk = n - NQ_;
                    kb[(((b * HKV_ + (nk >> 3)) * S_) + s) * QB_ + (nk & 7)] = f2bf(fast_tanh(pre));
                } else {
                    int nv = n - NQ_ - 16;
                    int hv = nv >> 4, vb = nv & 15;
                    u16 sig = f2bf(fast_sigmoid(pre));
                    if (s > 0)
                        vt[((b * HKV_ + hv) * VB_ + vb) * S_ + (s - 1)] = sig;   // suffix shift
                    if (s == S_ - 1)
                        vt[((b * HKV_ + hv) * VB_ + vb) * S_ + (S_ - 1)] = 0;
                }
            }
        }
    }
}

// ------------------------------------------------- K2: fused windowed attention
// grid 512 = 32 row-blocks x 16 bh; block 512 (8 waves = 2 J-groups x 4 row-waves)
// fixed-max softmax (scores provably in (-16,17) -> M=17), J-partials merge by plain sum
__global__ __launch_bounds__(512, 4) void k2_attn(
    const u16* __restrict__ qb, const u16* __restrict__ kb, const u16* __restrict__ vt,
    const float* __restrict__ vemb0, const float* __restrict__ vemb1,
    float* __restrict__ AO)
{
    __shared__ __align__(16) u16 ks[2][2][96 * 8];     // [group][dbuf][rows 0..95]
    __shared__ __align__(16) u16 psa[8][16 * 72];
    __shared__ __align__(16) float Om[8][16][17];
    __shared__ float lv[8][16];

    const int tid = threadIdx.x;
    const int bid = blockIdx.x;
    const int rb = bid >> 4;
    const int r  = (rb < 16) ? (31 - rb) : (rb - 16);  // complementary pairing: work(bid)+work(bid+256) const
    const int I0 = r * 64;
    const int nJ = r + 1;
    const int bh = bid & 15;
    const int b = bh >> 3, h = bh & 7, hkv = h >> 2;

    const int qhb = ((b * H_ + h) * S_) * QB_;
    const int khb = ((b * HKV_ + hkv) * S_) * QB_;
    const int vhb = ((b * HKV_ + hkv) * VB_) * S_;

    const int w = tid >> 6, lane = tid & 63;
    const int g = w >> 2, wr = w & 3;
    const int li = lane & 15, lo4 = lane >> 4;
    const int tloc = tid & 255;

    u16* psw = psa[w];

    // hoist Q fragments (direct from global; zero-pad rows < 0)
    s16x8 af[8];
    {
        const int gr0 = I0 - 31 + 16 * wr + li + lo4;
        const u16* qp = qb + qhb + gr0 * QB_;
        #pragma unroll
        for (int kk = 0; kk < 8; ++kk) {
            s16x8 v = {0, 0, 0, 0, 0, 0, 0, 0};
            if (gr0 + 4 * kk >= 0) v = *(const s16x8*)(qp + kk * 32);
            af[kk] = v;
        }
    }

    int iv[4];
    float binv[4];
    #pragma unroll
    for (int reg = 0; reg < 4; ++reg) {
        iv[reg] = I0 + 16 * wr + 4 * lo4 + reg;
        binv[reg] = 1.0f / (float)(iv[reg] + 1);
    }

    f32x4 O = (f32x4){0.f, 0.f, 0.f, 0.f};
    float lsum[4] = {0.f, 0.f, 0.f, 0.f};

    const u16* vtp = vt + vhb + li * S_ + 8 * lo4;

    // prologue: stage tile jt = g into buf 0
    if (g < nJ && tloc < 96) {
        int gr = 64 * g - 31 + tloc;
        s16x8 v = {0, 0, 0, 0, 0, 0, 0, 0};
        if (gr >= 0) v = *(const s16x8*)(kb + khb + gr * QB_);
        *(s16x8*)&ks[g][0][tloc * 8] = v;
    }
    __syncthreads();

    const int nT = (nJ + 1) >> 1;
    for (int t = 0; t < nT; ++t) {
        const int cb = t & 1;
        const int jt = 2 * t + g;

        // T14 split: issue next-tile global load EARLY (reg), ds_write LATE (after compute)
        const bool do_stage = ((jt + 2) < nJ) && (tloc < 96);
        s16x8 stg;
        if (do_stage)
            stg = *(const s16x8*)(kb + khb + (64 * (jt + 2) - 31 + tloc) * QB_);

        if (jt < nJ) {
            // QK^T with implicit window-unfold (K=256).
            // Dedup: frag(ns,kk) reads LDS row 4*(4ns+kk)+(li+lo4) -> depends only on
            // m = 4ns+kk: 20 distinct ds_read_b128 instead of 32 (same addresses as r2).
            const u16* kbuf = &ks[g][cb][(li + lo4) * 8];
            f32x4 sacc[4];
            #pragma unroll
            for (int ns = 0; ns < 4; ++ns) sacc[ns] = (f32x4){0.f, 0.f, 0.f, 0.f};
            #pragma unroll
            for (int m = 0; m < 20; ++m) {
                s16x8 f = *(const s16x8*)(kbuf + 32 * m);
                #pragma unroll
                for (int kk = (m & 3); kk < 8; kk += 4) {
                    int ns = (m - kk) >> 2;
                    if (ns >= 0 && ns < 4)
                        sacc[ns] = mfma16(af[kk], f, sacc[ns]);
                }
            }
            // bias + strict mask + fixed-max exp; P -> per-wave LDS
            const int J0 = jt * 64;
            int jv[4];
            #pragma unroll
            for (int ns = 0; ns < 4; ++ns) jv[ns] = J0 + 16 * ns + li;
            #pragma unroll
            for (int reg = 0; reg < 4; ++reg) {
                #pragma unroll
                for (int ns = 0; ns < 4; ++ns) {
                    float s = fmaf(sacc[ns][reg], SCALE_, (float)jv[ns] * binv[reg]);
                    float p = (jv[ns] < iv[reg]) ? __expf(s - MFIX_) : 0.0f;
                    lsum[reg] += p;
                    psw[(4 * lo4 + reg) * 72 + 16 * ns + li] = f2bf(p);
                }
            }
            // PV: P from LDS, V^T direct from global (L2-resident)
            #pragma unroll
            for (int kk2 = 0; kk2 < 2; ++kk2) {
                s16x8 pa = *(const s16x8*)&psw[li * 72 + 32 * kk2 + 8 * lo4];
                s16x8 pb = *(const s16x8*)(vtp + J0 + 32 * kk2);
                O = mfma16(pa, pb, O);
            }
        }

        if (do_stage)
            *(s16x8*)&ks[g][cb ^ 1][tloc * 8] = stg;

        __syncthreads();
    }

    // publish partials (plain-sum merge: fixed max => no exp rescale)
    #pragma unroll
    for (int reg = 0; reg < 4; ++reg) {
        float l = lsum[reg];
        l += __shfl_xor(l, 1);
        l += __shfl_xor(l, 2);
        l += __shfl_xor(l, 4);
        l += __shfl_xor(l, 8);
        Om[w][4 * lo4 + reg][li] = O[reg];
        if (li == 0) lv[w][4 * lo4 + reg] = l;
    }
    __syncthreads();

    if (g == 0) {
        const int hc = h * VB_ + li;
        const float e0 = vemb0[hc], e1 = vemb1[hc];
        #pragma unroll
        for (int reg = 0; reg < 4; ++reg) {
            const int row = 4 * lo4 + reg;
            float Oc = Om[w][row][li] + Om[w + 4][row][li];
            float lc = lv[w][row] + lv[w + 4][row];
            float o = Oc / fmaxf(lc, 1e-30f);
            const int s = I0 + 16 * wr + row;
            AO[(b * S_ + s) * HVB_ + hc] = e0 + o * (e1 - e0);
        }
    }
}

// ------------------------------------------------- K3: AO @ Wo^T (bf16x3)
// block 256 (4 waves), 16 rows x 512 cols; wave owns 8 frags
__global__ __launch_bounds__(256) void k3_out(
    const float* __restrict__ AO,
    const u16* __restrict__ W2o_hi, const u16* __restrict__ W2o_lo,
    float* __restrict__ out)
{
    __shared__ __align__(16) u32 Ahi[16 * 64];
    __shared__ __align__(16) u32 Alo[16 * 64];
    char* AhiB = (char*)Ahi;
    char* AloB = (char*)Alo;
    const int tid = threadIdx.x;
    const int r0 = blockIdx.x * 16;

    #pragma unroll
    for (int it = 0; it < 2; ++it) {
        int v4 = it * 256 + tid;            // 512 f32x4 = 16 x 128
        int m = v4 >> 5, c4 = v4 & 31;
        f32x4 x = *(const f32x4*)&AO[(r0 + m) * HVB_ + 4 * c4];
        u16 h0 = f2bf(x[0]), h1 = f2bf(x[1]), h2 = f2bf(x[2]), h3 = f2bf(x[3]);
        u16 l0 = f2bf(x[0] - bf2f(h0)), l1 = f2bf(x[1] - bf2f(h1));
        u16 l2 = f2bf(x[2] - bf2f(h2)), l3 = f2bf(x[3] - bf2f(h3));
        int byt = (c4 * 8) ^ ((m & 7) << 4);
        *(u32x2*)(AhiB + m * 256 + byt) = (u32x2){(u32)h0 | ((u32)h1 << 16), (u32)h2 | ((u32)h3 << 16)};
        *(u32x2*)(AloB + m * 256 + byt) = (u32x2){(u32)l0 | ((u32)l1 << 16), (u32)l2 | ((u32)l3 << 16)};
    }
    __syncthreads();

    const int wv = tid >> 6, lane = tid & 63;
    const int li = lane & 15, lo4 = lane >> 4;

    f32x4 acc[8];
    #pragma unroll
    for (int f = 0; f < 8; ++f) acc[f] = (f32x4){0.f, 0.f, 0.f, 0.f};

    #pragma unroll
    for (int kc = 0; kc < 4; ++kc) {
        int off = (64 * kc + 16 * lo4) ^ ((li & 7) << 4);
        s16x8 ah = *(const s16x8*)(AhiB + li * 256 + off);
        s16x8 al = *(const s16x8*)(AloB + li * 256 + off);
        #pragma unroll
        for (int f = 0; f < 8; ++f) {
            int o = wv * 128 + f * 16 + li;
            int bidx = (kc * HID_ + o) * 32 + 8 * lo4;
            s16x8 bh = *(const s16x8*)&W2o_hi[bidx];
            s16x8 bl = *(const s16x8*)&W2o_lo[bidx];
            acc[f] = mfma16(ah, bh, acc[f]);
            acc[f] = mfma16(ah, bl, acc[f]);
            acc[f] = mfma16(al, bh, acc[f]);
        }
    }

    #pragma unroll
    for (int f = 0; f < 8; ++f) {
        int o = wv * 128 + f * 16 + li;
        #pragma unroll
        for (int reg = 0; reg < 4; ++reg)
            out[(r0 + 4 * lo4 + reg) * HID_ + o] = acc[f][reg];
    }
}

// ------------------------------------------------- launch
extern "C" void kernel_launch(void* const* d_in, const int* in_sizes, int n_in,
                              void* d_out, int out_size, void* d_ws, size_t ws_size,
                              hipStream_t stream)
{
    (void)in_sizes; (void)n_in; (void)out_size;
    const float* hidden = (const float*)d_in[0];
    const float* Wq = (const float*)d_in[1];
    const float* Wk = (const float*)d_in[2];
    const float* Wv = (const float*)d_in[3];
    const float* Wo = (const float*)d_in[4];
    const float* ve0 = (const float*)d_in[5];
    const float* ve1 = (const float*)d_in[6];
    float* out = (float*)d_out;

    char* base = (char*)d_ws;
    u16* qb    = (u16*)(base);                      // [B,H,S,8]    524288 B
    u16* kb    = (u16*)(base + 524288);             // [B,HKV,S,8]  131072 B
    u16* vt    = (u16*)(base + 655360);             // [B,HKV,16,S] 262144 B (shifted, transposed)
    float* AO  = (float*)(base + 917504);           // [B*S,128]    2097152 B
    u16* W2c_hi = (u16*)(base + 3014656);           // 114688 B
    u16* W2c_lo = (u16*)(base + 3129344);           // 114688 B
    u16* W2o_hi = (u16*)(base + 3244032);           // 131072 B
    u16* W2o_lo = (u16*)(base + 3375104);           // 131072 B -> end 3506176
    if (ws_size < 3506176) return;

    hipLaunchKernelGGL(k0_convert, dim3(256), dim3(256), 0, stream,
                       Wq, Wk, Wv, Wo, W2c_hi, W2c_lo, W2o_hi, W2o_lo);
    hipLaunchKernelGGL(k1_proj, dim3(256), dim3(256), 0, stream,
                       hidden, W2c_hi, W2c_lo, qb, kb, vt);
    hipLaunchKernelGGL(k2_attn, dim3(512), dim3(512), 0, stream,
                       qb, kb, vt, ve0, ve1, AO);
    hipLaunchKernelGGL(k3_out, dim3(256), dim3(256), 0, stream,
                       AO, W2o_hi, W2o_lo, out);
}